// Round 4
// baseline (358.285 us; speedup 1.0000x reference)
//
#include <hip/hip_runtime.h>

#define B_ 32
#define C_ 128
#define H_ 64
#define W_ 64
#define HW_ (H_*W_)
#define HBLK 4
#define NWG_ (B_*(H_/HBLK))   // 512 workgroups for fused kernels
#define EPS_ 1e-5f

typedef __attribute__((ext_vector_type(8))) short s8v;   // 8 bf16 (4 VGPRs)
typedef __attribute__((ext_vector_type(4))) float f4v;   // MFMA accumulator
typedef unsigned short u16;

__device__ __forceinline__ short f2bf(float f) {
    union { float f; unsigned u; } v; v.f = f;
    unsigned r = v.u + 0x7fffu + ((v.u >> 16) & 1u);     // RNE
    return (short)(r >> 16);
}
__device__ __forceinline__ float bf2f(u16 u) {
    union { unsigned u; float f; } v; v.u = ((unsigned)u) << 16; return v.f;
}
// bank swizzle: bijective per row (flips byte bits 4-6), varies within each
// quarter-wave for BOTH the phase-1 write (p = r*64+q*4+j) and the phase-2
// read (p = nt*16+q) access patterns.
__device__ __forceinline__ int swz(int p) {
    return (((p & 7) ^ ((p >> 3) & 7)) << 4);
}

// Pack pw (layout [o][c], fp32) into exact A-fragment order, bf16:
// frag[((mt*4+kk)*64 + lane)*8 + j] = pw[o = mt*16+(lane&15)][c = kk*32+(lane>>4)*8+j]
__global__ __launch_bounds__(256) void prep_wfrag(const float* __restrict__ pw1,
                                                  const float* __restrict__ pw2,
                                                  short* __restrict__ f1,
                                                  short* __restrict__ f2) {
    int t = blockIdx.x * 256 + threadIdx.x;
    if (t >= 16384) return;
    int j    = t & 7;
    int lane = (t >> 3) & 63;
    int kk   = (t >> 9) & 3;
    int mt   = t >> 11;
    int o = mt * 16 + (lane & 15);
    int c = kk * 32 + (lane >> 4) * 8 + j;
    f1[t] = f2bf(pw1[o * C_ + c]);
    f2[t] = f2bf(pw2[o * C_ + c]);
}

// One WG per (n, 4-row slab). Phase 1: (BN-on-read) + relu + depthwise3x3 ->
// bf16 LDS xT[256 px][128 c], XOR-swizzled. Phase 2: MFMA GEMM 128o x 256p.
// Epilogue: fused partial stats + LDS-staged transpose -> contiguous 512B
// global stores of bf16 y (NCHW).
template<int BF16IN>
__global__ __launch_bounds__(512, 4) void fused_block(
    const void*  __restrict__ xin_,
    const float* __restrict__ scale_in,   // BN1 params (BF16IN=1 only)
    const float* __restrict__ shift_in,
    const float* __restrict__ dww,        // [C][9]
    const short* __restrict__ wfrag,      // pre-packed A-frags, bf16
    u16*         __restrict__ yout,       // pre-BN y, bf16 NCHW
    float*       __restrict__ psum,       // [NWG_][C_]
    float*       __restrict__ psq)        // [NWG_][C_]
{
    __shared__ short xT[256 * 128];       // 64 KiB: row p (256B) x col c, swizzled

    const int wg   = blockIdx.x;
    const int n    = wg >> 4;
    const int h0   = (wg & 15) * HBLK;
    const int t    = threadIdx.x;
    const int lane = t & 63;
    const int wv   = t >> 6;              // 8 waves
    const int r    = lane >> 4;           // row-in-slab 0..3
    const int q    = lane & 15;           // px quad 0..15
    const int p0   = r * 64 + q * 4;      // first pixel this lane produces

    // ---- phase 1: depthwise; wave wv owns channels wv*16 .. wv*16+15 ----
    for (int g = 0; g < 2; ++g) {
        const int c0 = wv * 16 + g * 8;
        s8v row0, row1, row2, row3;
        #pragma unroll
        for (int cc = 0; cc < 8; ++cc) {
            const int c = c0 + cc;
            float sc = 1.f, sh = 0.f;
            if (BF16IN) { sc = scale_in[c]; sh = shift_in[c]; }
            const float* wc = dww + c * 9;
            float4 v[3];
            #pragma unroll
            for (int k = 0; k < 3; ++k) {
                const int hin = h0 + r - 1 + k;
                float4 val = make_float4(0.f, 0.f, 0.f, 0.f);
                if (hin >= 0 && hin < H_) {
                    if (BF16IN) {
                        const u16* xc = (const u16*)xin_ + ((size_t)(n * C_ + c)) * HW_;
                        ushort4 u = *(const ushort4*)(xc + hin * W_ + q * 4);
                        val = make_float4(bf2f(u.x), bf2f(u.y), bf2f(u.z), bf2f(u.w));
                    } else {
                        const float* xc = (const float*)xin_ + ((size_t)(n * C_ + c)) * HW_;
                        val = *(const float4*)(xc + hin * W_ + q * 4);
                    }
                    val.x = fmaxf(fmaf(val.x, sc, sh), 0.f);
                    val.y = fmaxf(fmaf(val.y, sc, sh), 0.f);
                    val.z = fmaxf(fmaf(val.z, sc, sh), 0.f);
                    val.w = fmaxf(fmaf(val.w, sc, sh), 0.f);
                }
                v[k] = val;
            }
            float lf0 = __shfl_up(v[0].w, 1), lf1 = __shfl_up(v[1].w, 1), lf2 = __shfl_up(v[2].w, 1);
            float rt0 = __shfl_down(v[0].x, 1), rt1 = __shfl_down(v[1].x, 1), rt2 = __shfl_down(v[2].x, 1);
            if (q == 0)  { lf0 = 0.f; lf1 = 0.f; lf2 = 0.f; }
            if (q == 15) { rt0 = 0.f; rt1 = 0.f; rt2 = 0.f; }
            const float e0[6] = {lf0, v[0].x, v[0].y, v[0].z, v[0].w, rt0};
            const float e1[6] = {lf1, v[1].x, v[1].y, v[1].z, v[1].w, rt1};
            const float e2[6] = {lf2, v[2].x, v[2].y, v[2].z, v[2].w, rt2};
            #pragma unroll
            for (int j = 0; j < 4; ++j) {
                float a;
                a = wc[0] * e0[j];
                a = fmaf(wc[1], e0[j+1], a); a = fmaf(wc[2], e0[j+2], a);
                a = fmaf(wc[3], e1[j],   a); a = fmaf(wc[4], e1[j+1], a); a = fmaf(wc[5], e1[j+2], a);
                a = fmaf(wc[6], e2[j],   a); a = fmaf(wc[7], e2[j+1], a); a = fmaf(wc[8], e2[j+2], a);
                const short bv = f2bf(a);
                if (j == 0) row0[cc] = bv;
                else if (j == 1) row1[cc] = bv;
                else if (j == 2) row2[cc] = bv;
                else row3[cc] = bv;
            }
        }
        const int cb = c0 * 2;            // byte col, 16B-aligned
        *(s8v*)((char*)xT + (p0 + 0) * 256 + (cb ^ swz(p0 + 0))) = row0;
        *(s8v*)((char*)xT + (p0 + 1) * 256 + (cb ^ swz(p0 + 1))) = row1;
        *(s8v*)((char*)xT + (p0 + 2) * 256 + (cb ^ swz(p0 + 2))) = row2;
        *(s8v*)((char*)xT + (p0 + 3) * 256 + (cb ^ swz(p0 + 3))) = row3;
    }
    __syncthreads();

    // ---- phase 2: GEMM; wave wv owns o-tile wv (16 o-rows) x 256 px ----
    s8v a[4];
    #pragma unroll
    for (int kk = 0; kk < 4; ++kk)
        a[kk] = *(const s8v*)&wfrag[((wv * 4 + kk) * 64 + lane) * 8];

    f4v acc[16];
    #pragma unroll
    for (int nt = 0; nt < 16; ++nt) acc[nt] = (f4v)(0.f);

    #pragma unroll
    for (int nt = 0; nt < 16; ++nt) {
        const int p = nt * 16 + q;
        const int rowb = p * 256;
        const int sw = swz(p);
        #pragma unroll
        for (int kk = 0; kk < 4; ++kk) {
            s8v b = *(const s8v*)((char*)xT + rowb + ((kk * 64 + r * 16) ^ sw));
            acc[nt] = __builtin_amdgcn_mfma_f32_16x16x32_bf16(a[kk], b, acc[nt], 0, 0, 0);
        }
    }

    // ---- fused partial stats (from fp32 acc, one 512B burst per WG) ----
    #pragma unroll
    for (int ri = 0; ri < 4; ++ri) {
        const int ot = r * 4 + ri;
        float s = 0.f, qq = 0.f;
        #pragma unroll
        for (int nt = 0; nt < 16; ++nt) {
            const float val = acc[nt][ri];
            s += val; qq = fmaf(val, val, qq);
        }
        s += __shfl_xor(s, 1); qq += __shfl_xor(qq, 1);
        s += __shfl_xor(s, 2); qq += __shfl_xor(qq, 2);
        s += __shfl_xor(s, 4); qq += __shfl_xor(qq, 4);
        s += __shfl_xor(s, 8); qq += __shfl_xor(qq, 8);
        if (q == 0) {
            const int og = wv * 16 + ot;
            psum[(size_t)wg * C_ + og] = s;
            psq [(size_t)wg * C_ + og] = qq;
        }
    }

    // ---- epilogue: LDS-staged transpose -> contiguous 512B stores ----
    __syncthreads();                      // everyone done reading xT
    u16* stage = (u16*)xT;                // [8 wv][16 ot][256 px]
    #pragma unroll
    for (int ri = 0; ri < 4; ++ri) {
        const int ot = r * 4 + ri;
        #pragma unroll
        for (int nt = 0; nt < 16; ++nt)
            stage[wv * 4096 + ot * 256 + nt * 16 + q] = (u16)f2bf(acc[nt][ri]);
    }
    u16* yb = yout + ((size_t)(n * C_ + wv * 16)) * HW_ + h0 * W_;
    #pragma unroll
    for (int oi = 0; oi < 8; ++oi) {
        const int ot2 = oi * 2 + (lane >> 5);
        uint4 v = *(const uint4*)((const char*)stage + wv * 8192 + ot2 * 512 + (lane & 31) * 16);
        *(uint4*)((char*)(yb + (size_t)ot2 * HW_) + (lane & 31) * 16) = v;
    }
}

// One WG per channel: reduce NWG_ partials -> scale/shift.
__global__ __launch_bounds__(256) void stats_reduce(const float* __restrict__ psum,
                                                    const float* __restrict__ psq,
                                                    const float* __restrict__ gamma,
                                                    const float* __restrict__ beta,
                                                    float* __restrict__ scale,
                                                    float* __restrict__ shift) {
    const int o = blockIdx.x;
    const int t = threadIdx.x;
    float s = 0.f, q = 0.f;
    for (int i = t; i < NWG_; i += 256) {
        s += psum[(size_t)i * C_ + o];
        q += psq [(size_t)i * C_ + o];
    }
    #pragma unroll
    for (int off = 32; off > 0; off >>= 1) {
        s += __shfl_down(s, off);
        q += __shfl_down(q, off);
    }
    __shared__ float rs[4], rq[4];
    const int wid = t >> 6;
    if ((t & 63) == 0) { rs[wid] = s; rq[wid] = q; }
    __syncthreads();
    if (t == 0) {
        float S = rs[0] + rs[1] + rs[2] + rs[3];
        float Q = rq[0] + rq[1] + rq[2] + rq[3];
        const float inv = 1.f / (float)(B_ * HW_);
        float mean = S * inv;
        float var  = Q * inv - mean * mean;
        float sc   = gamma[o] * rsqrtf(var + EPS_);
        scale[o] = sc;
        shift[o] = fmaf(-mean, sc, beta[o]);
    }
}

// BN apply: read bf16 y2, write fp32 out.
__global__ __launch_bounds__(256) void apply_bn(const u16* __restrict__ y,
                                                float* __restrict__ out,
                                                const float* __restrict__ scale,
                                                const float* __restrict__ shift) {
    const size_t total8 = (size_t)B_ * C_ * HW_ / 8;
    const size_t stride = (size_t)gridDim.x * 256;
    for (size_t i = (size_t)blockIdx.x * 256 + threadIdx.x; i < total8; i += stride) {
        const size_t e = i * 8;
        const int c = (int)((e >> 12) & (C_ - 1));
        const float sc = scale[c], sh = shift[c];
        s8v v = *(const s8v*)(y + e);
        float4 o1, o2;
        o1.x = fmaf(bf2f((u16)v[0]), sc, sh);
        o1.y = fmaf(bf2f((u16)v[1]), sc, sh);
        o1.z = fmaf(bf2f((u16)v[2]), sc, sh);
        o1.w = fmaf(bf2f((u16)v[3]), sc, sh);
        o2.x = fmaf(bf2f((u16)v[4]), sc, sh);
        o2.y = fmaf(bf2f((u16)v[5]), sc, sh);
        o2.z = fmaf(bf2f((u16)v[6]), sc, sh);
        o2.w = fmaf(bf2f((u16)v[7]), sc, sh);
        *(float4*)(out + e)     = o1;
        *(float4*)(out + e + 4) = o2;
    }
}

extern "C" void kernel_launch(void* const* d_in, const int* in_sizes, int n_in,
                              void* d_out, int out_size, void* d_ws, size_t ws_size,
                              hipStream_t stream) {
    const float* x      = (const float*)d_in[0];
    const float* dw1    = (const float*)d_in[1];
    const float* pw1    = (const float*)d_in[2];
    const float* gamma1 = (const float*)d_in[3];
    const float* beta1  = (const float*)d_in[4];
    const float* dw2    = (const float*)d_in[5];
    const float* pw2    = (const float*)d_in[6];
    const float* gamma2 = (const float*)d_in[7];
    const float* beta2  = (const float*)d_in[8];
    float* out = (float*)d_out;
    char*  ws  = (char*)d_ws;

    short* wf1    = (short*)(ws);                    // 32 KiB
    short* wf2    = (short*)(ws + 32768);            // 32 KiB
    float* scale1 = (float*)(ws + 65536);
    float* shift1 = (float*)(ws + 66048);
    float* scale2 = (float*)(ws + 66560);
    float* shift2 = (float*)(ws + 67072);
    float* psum   = (float*)(ws + 67584);            // 256 KiB
    float* psq    = (float*)(ws + 67584 + 262144);   // 256 KiB
    u16*   y1     = (u16*)(ws + 591872);             // 32 MiB bf16
    u16*   y2     = (u16*)(ws + 591872 + 33554432);  // 32 MiB bf16

    prep_wfrag<<<64, 256, 0, stream>>>(pw1, pw2, wf1, wf2);
    fused_block<0><<<NWG_, 512, 0, stream>>>(x, nullptr, nullptr, dw1, wf1, y1, psum, psq);
    stats_reduce<<<C_, 256, 0, stream>>>(psum, psq, gamma1, beta1, scale1, shift1);
    fused_block<1><<<NWG_, 512, 0, stream>>>(y1, scale1, shift1, dw2, wf2, y2, psum, psq);
    stats_reduce<<<C_, 256, 0, stream>>>(psum, psq, gamma2, beta2, scale2, shift2);
    apply_bn<<<2048, 256, 0, stream>>>(y2, out, scale2, shift2);
}

// Round 6
// 352.550 us; speedup vs baseline: 1.0163x; 1.0163x over previous
//
#include <hip/hip_runtime.h>

#define B_ 32
#define C_ 128
#define H_ 64
#define W_ 64
#define HW_ (H_*W_)
#define HBLK 4
#define NWG_ (B_*(H_/HBLK))   // 512 workgroups for fused kernels
#define EPS_ 1e-5f

typedef __attribute__((ext_vector_type(8))) short s8v;   // 8 bf16 (4 VGPRs)
typedef __attribute__((ext_vector_type(4))) float f4v;   // MFMA accumulator
typedef unsigned short u16;

__device__ __forceinline__ short f2bf(float f) {
    union { float f; unsigned u; } v; v.f = f;
    unsigned r = v.u + 0x7fffu + ((v.u >> 16) & 1u);     // RNE
    return (short)(r >> 16);
}
__device__ __forceinline__ float bf2f(u16 u) {
    union { unsigned u; float f; } v; v.u = ((unsigned)u) << 16; return v.f;
}
// bank swizzle on byte offset within a 256B row. Bijective per row (XOR of a
// row-dependent constant). Bit pattern chosen so:
//  - phase-1 s8v writes (p = r*64+q*4+j, fixed j per inst) spread evenly
//  - phase-2 b128 reads (p = nt*16+q) hit 16 distinct 16B slots (floor)
__device__ __forceinline__ int swz(int p) {
    return ((((p & 7) ^ ((p >> 3) & 7)) << 4) | ((p & 1) << 7));
}

// Pack pw (layout [o][c], fp32) into exact A-fragment order, bf16:
// frag[((mt*4+kk)*64 + lane)*8 + j] = pw[o = mt*16+(lane&15)][c = kk*32+(lane>>4)*8+j]
__global__ __launch_bounds__(256) void prep_wfrag(const float* __restrict__ pw1,
                                                  const float* __restrict__ pw2,
                                                  short* __restrict__ f1,
                                                  short* __restrict__ f2) {
    int t = blockIdx.x * 256 + threadIdx.x;
    if (t >= 16384) return;
    int j    = t & 7;
    int lane = (t >> 3) & 63;
    int kk   = (t >> 9) & 3;
    int mt   = t >> 11;
    int o = mt * 16 + (lane & 15);
    int c = kk * 32 + (lane >> 4) * 8 + j;
    f1[t] = f2bf(pw1[o * C_ + c]);
    f2[t] = f2bf(pw2[o * C_ + c]);
}

// One WG per (n, 4-row slab). Phase 1: (BN-on-read) + relu + depthwise3x3 ->
// bf16 LDS xT[256 px][128 c], XOR-swizzled, with explicit 12-load batches for
// memory-level parallelism. Phase 2: MFMA GEMM 128o x 256p. Epilogue: fused
// partial stats + LDS-staged transpose -> contiguous 512B stores (bf16 NCHW).
template<int BF16IN>
__global__ __launch_bounds__(512, 4) void fused_block(
    const void*  __restrict__ xin_,
    const float* __restrict__ scale_in,   // BN1 params (BF16IN=1 only)
    const float* __restrict__ shift_in,
    const float* __restrict__ dww,        // [C][9]
    const short* __restrict__ wfrag,      // pre-packed A-frags, bf16
    u16*         __restrict__ yout,       // pre-BN y, bf16 NCHW
    float*       __restrict__ psum,       // [NWG_][C_]
    float*       __restrict__ psq)        // [NWG_][C_]
{
    __shared__ short xT[256 * 128];       // 64 KiB: row p (256B) x col c, swizzled

    const int wg   = blockIdx.x;
    const int n    = wg >> 4;
    const int h0   = (wg & 15) * HBLK;
    const int t    = threadIdx.x;
    const int lane = t & 63;
    const int wv   = t >> 6;              // 8 waves
    const int r    = lane >> 4;           // row-in-slab 0..3
    const int q    = lane & 15;           // px quad 0..15
    const int p0   = r * 64 + q * 4;      // first pixel this lane produces

    // ---- phase 1: depthwise; wave wv owns channels wv*16 .. wv*16+15 ----
    for (int g = 0; g < 2; ++g) {
        const int c0 = wv * 16 + g * 8;
        s8v rows[4];
        #pragma unroll
        for (int half = 0; half < 2; ++half) {
            // batch-issue all 12 loads (clamped rows; zeroing deferred)
            float4  rf[4][3];
            ushort4 rb[4][3];
            #pragma unroll
            for (int cc = 0; cc < 4; ++cc) {
                const int c = c0 + half * 4 + cc;
                #pragma unroll
                for (int k = 0; k < 3; ++k) {
                    const int hin = h0 + r - 1 + k;
                    const int hc  = hin < 0 ? 0 : (hin >= H_ ? H_ - 1 : hin);
                    if (BF16IN) {
                        const u16* xc = (const u16*)xin_ + ((size_t)(n * C_ + c)) * HW_;
                        rb[cc][k] = *(const ushort4*)(xc + hc * W_ + q * 4);
                    } else {
                        const float* xc = (const float*)xin_ + ((size_t)(n * C_ + c)) * HW_;
                        rf[cc][k] = *(const float4*)(xc + hc * W_ + q * 4);
                    }
                }
            }
            // consume the batch
            #pragma unroll
            for (int cc = 0; cc < 4; ++cc) {
                const int c = c0 + half * 4 + cc;
                float sc = 1.f, sh = 0.f;
                if (BF16IN) { sc = scale_in[c]; sh = shift_in[c]; }
                const float* wc = dww + c * 9;
                float4 v[3];
                #pragma unroll
                for (int k = 0; k < 3; ++k) {
                    const int hin = h0 + r - 1 + k;
                    float4 val;
                    if (BF16IN) {
                        const ushort4 u = rb[cc][k];
                        val = make_float4(bf2f(u.x), bf2f(u.y), bf2f(u.z), bf2f(u.w));
                    } else {
                        val = rf[cc][k];
                    }
                    val.x = fmaxf(fmaf(val.x, sc, sh), 0.f);
                    val.y = fmaxf(fmaf(val.y, sc, sh), 0.f);
                    val.z = fmaxf(fmaf(val.z, sc, sh), 0.f);
                    val.w = fmaxf(fmaf(val.w, sc, sh), 0.f);
                    if (hin < 0 || hin >= H_) val = make_float4(0.f, 0.f, 0.f, 0.f);
                    v[k] = val;
                }
                float lf0 = __shfl_up(v[0].w, 1), lf1 = __shfl_up(v[1].w, 1), lf2 = __shfl_up(v[2].w, 1);
                float rt0 = __shfl_down(v[0].x, 1), rt1 = __shfl_down(v[1].x, 1), rt2 = __shfl_down(v[2].x, 1);
                if (q == 0)  { lf0 = 0.f; lf1 = 0.f; lf2 = 0.f; }
                if (q == 15) { rt0 = 0.f; rt1 = 0.f; rt2 = 0.f; }
                const float e0[6] = {lf0, v[0].x, v[0].y, v[0].z, v[0].w, rt0};
                const float e1[6] = {lf1, v[1].x, v[1].y, v[1].z, v[1].w, rt1};
                const float e2[6] = {lf2, v[2].x, v[2].y, v[2].z, v[2].w, rt2};
                #pragma unroll
                for (int j = 0; j < 4; ++j) {
                    float a;
                    a = wc[0] * e0[j];
                    a = fmaf(wc[1], e0[j+1], a); a = fmaf(wc[2], e0[j+2], a);
                    a = fmaf(wc[3], e1[j],   a); a = fmaf(wc[4], e1[j+1], a); a = fmaf(wc[5], e1[j+2], a);
                    a = fmaf(wc[6], e2[j],   a); a = fmaf(wc[7], e2[j+1], a); a = fmaf(wc[8], e2[j+2], a);
                    rows[j][half * 4 + cc] = f2bf(a);
                }
            }
        }
        const int cb = c0 * 2;            // byte col, 16B-aligned
        *(s8v*)((char*)xT + (p0 + 0) * 256 + (cb ^ swz(p0 + 0))) = rows[0];
        *(s8v*)((char*)xT + (p0 + 1) * 256 + (cb ^ swz(p0 + 1))) = rows[1];
        *(s8v*)((char*)xT + (p0 + 2) * 256 + (cb ^ swz(p0 + 2))) = rows[2];
        *(s8v*)((char*)xT + (p0 + 3) * 256 + (cb ^ swz(p0 + 3))) = rows[3];
    }
    __syncthreads();

    // ---- phase 2: GEMM; wave wv owns o-tile wv (16 o-rows) x 256 px ----
    s8v a[4];
    #pragma unroll
    for (int kk = 0; kk < 4; ++kk)
        a[kk] = *(const s8v*)&wfrag[((wv * 4 + kk) * 64 + lane) * 8];

    f4v acc[16];
    #pragma unroll
    for (int nt = 0; nt < 16; ++nt) acc[nt] = (f4v)(0.f);

    #pragma unroll
    for (int nt = 0; nt < 16; ++nt) {
        const int p = nt * 16 + q;
        const int rowb = p * 256;
        const int sw = swz(p);
        #pragma unroll
        for (int kk = 0; kk < 4; ++kk) {
            s8v b = *(const s8v*)((char*)xT + rowb + ((kk * 64 + r * 16) ^ sw));
            acc[nt] = __builtin_amdgcn_mfma_f32_16x16x32_bf16(a[kk], b, acc[nt], 0, 0, 0);
        }
    }

    // ---- fused partial stats (one 512B burst per WG per buffer) ----
    #pragma unroll
    for (int ri = 0; ri < 4; ++ri) {
        const int ot = r * 4 + ri;
        float s = 0.f, qq = 0.f;
        #pragma unroll
        for (int nt = 0; nt < 16; ++nt) {
            const float val = acc[nt][ri];
            s += val; qq = fmaf(val, val, qq);
        }
        s += __shfl_xor(s, 1); qq += __shfl_xor(qq, 1);
        s += __shfl_xor(s, 2); qq += __shfl_xor(qq, 2);
        s += __shfl_xor(s, 4); qq += __shfl_xor(qq, 4);
        s += __shfl_xor(s, 8); qq += __shfl_xor(qq, 8);
        if (q == 0) {
            const int og = wv * 16 + ot;
            psum[(size_t)wg * C_ + og] = s;
            psq [(size_t)wg * C_ + og] = qq;
        }
    }

    // ---- epilogue: LDS-staged transpose -> contiguous 512B stores ----
    __syncthreads();                      // everyone done reading xT
    u16* stage = (u16*)xT;                // [8 wv][16 ot][256 px], ot-swizzled
    #pragma unroll
    for (int ri = 0; ri < 4; ++ri) {
        const int ot = r * 4 + ri;
        #pragma unroll
        for (int nt = 0; nt < 16; ++nt)
            stage[(wv * 4096 + ot * 256 + nt * 16 + q) ^ ((ot & 7) << 3)] = (u16)f2bf(acc[nt][ri]);
    }
    u16* yb = yout + ((size_t)(n * C_ + wv * 16)) * HW_ + h0 * W_;
    #pragma unroll
    for (int oi = 0; oi < 8; ++oi) {
        const int ot2 = oi * 2 + (lane >> 5);
        const char* sp = (const char*)stage +
            (((wv * 4096 + ot2 * 256 + (lane & 31) * 8) * 2) ^ ((ot2 & 7) << 4));
        uint4 v = *(const uint4*)sp;
        *(uint4*)((char*)(yb + (size_t)ot2 * HW_) + (lane & 31) * 16) = v;
    }
}

// One WG per channel: reduce NWG_ partials -> scale/shift.
__global__ __launch_bounds__(256) void stats_reduce(const float* __restrict__ psum,
                                                    const float* __restrict__ psq,
                                                    const float* __restrict__ gamma,
                                                    const float* __restrict__ beta,
                                                    float* __restrict__ scale,
                                                    float* __restrict__ shift) {
    const int o = blockIdx.x;
    const int t = threadIdx.x;
    float s = 0.f, q = 0.f;
    for (int i = t; i < NWG_; i += 256) {
        s += psum[(size_t)i * C_ + o];
        q += psq [(size_t)i * C_ + o];
    }
    #pragma unroll
    for (int off = 32; off > 0; off >>= 1) {
        s += __shfl_down(s, off);
        q += __shfl_down(q, off);
    }
    __shared__ float rs[4], rq[4];
    const int wid = t >> 6;
    if ((t & 63) == 0) { rs[wid] = s; rq[wid] = q; }
    __syncthreads();
    if (t == 0) {
        float S = rs[0] + rs[1] + rs[2] + rs[3];
        float Q = rq[0] + rq[1] + rq[2] + rq[3];
        const float inv = 1.f / (float)(B_ * HW_);
        float mean = S * inv;
        float var  = Q * inv - mean * mean;
        float sc   = gamma[o] * rsqrtf(var + EPS_);
        scale[o] = sc;
        shift[o] = fmaf(-mean, sc, beta[o]);
    }
}

// BN apply: read bf16 y2, write fp32 out.
__global__ __launch_bounds__(256) void apply_bn(const u16* __restrict__ y,
                                                float* __restrict__ out,
                                                const float* __restrict__ scale,
                                                const float* __restrict__ shift) {
    const size_t total8 = (size_t)B_ * C_ * HW_ / 8;
    const size_t stride = (size_t)gridDim.x * 256;
    for (size_t i = (size_t)blockIdx.x * 256 + threadIdx.x; i < total8; i += stride) {
        const size_t e = i * 8;
        const int c = (int)((e >> 12) & (C_ - 1));
        const float sc = scale[c], sh = shift[c];
        s8v v = *(const s8v*)(y + e);
        float4 o1, o2;
        o1.x = fmaf(bf2f((u16)v[0]), sc, sh);
        o1.y = fmaf(bf2f((u16)v[1]), sc, sh);
        o1.z = fmaf(bf2f((u16)v[2]), sc, sh);
        o1.w = fmaf(bf2f((u16)v[3]), sc, sh);
        o2.x = fmaf(bf2f((u16)v[4]), sc, sh);
        o2.y = fmaf(bf2f((u16)v[5]), sc, sh);
        o2.z = fmaf(bf2f((u16)v[6]), sc, sh);
        o2.w = fmaf(bf2f((u16)v[7]), sc, sh);
        *(float4*)(out + e)     = o1;
        *(float4*)(out + e + 4) = o2;
    }
}

extern "C" void kernel_launch(void* const* d_in, const int* in_sizes, int n_in,
                              void* d_out, int out_size, void* d_ws, size_t ws_size,
                              hipStream_t stream) {
    const float* x      = (const float*)d_in[0];
    const float* dw1    = (const float*)d_in[1];
    const float* pw1    = (const float*)d_in[2];
    const float* gamma1 = (const float*)d_in[3];
    const float* beta1  = (const float*)d_in[4];
    const float* dw2    = (const float*)d_in[5];
    const float* pw2    = (const float*)d_in[6];
    const float* gamma2 = (const float*)d_in[7];
    const float* beta2  = (const float*)d_in[8];
    float* out = (float*)d_out;
    char*  ws  = (char*)d_ws;

    short* wf1    = (short*)(ws);                    // 32 KiB
    short* wf2    = (short*)(ws + 32768);            // 32 KiB
    float* scale1 = (float*)(ws + 65536);
    float* shift1 = (float*)(ws + 66048);
    float* scale2 = (float*)(ws + 66560);
    float* shift2 = (float*)(ws + 67072);
    float* psum   = (float*)(ws + 67584);            // 256 KiB
    float* psq    = (float*)(ws + 67584 + 262144);   // 256 KiB
    u16*   y1     = (u16*)(ws + 591872);             // 32 MiB bf16
    u16*   y2     = (u16*)(ws + 591872 + 33554432);  // 32 MiB bf16

    prep_wfrag<<<64, 256, 0, stream>>>(pw1, pw2, wf1, wf2);
    fused_block<0><<<NWG_, 512, 0, stream>>>(x, nullptr, nullptr, dw1, wf1, y1, psum, psq);
    stats_reduce<<<C_, 256, 0, stream>>>(psum, psq, gamma1, beta1, scale1, shift1);
    fused_block<1><<<NWG_, 512, 0, stream>>>(y1, scale1, shift1, dw2, wf2, y2, psum, psq);
    stats_reduce<<<C_, 256, 0, stream>>>(psum, psq, gamma2, beta2, scale2, shift2);
    apply_bn<<<2048, 256, 0, stream>>>(y2, out, scale2, shift2);
}

// Round 7
// 277.969 us; speedup vs baseline: 1.2889x; 1.2683x over previous
//
#include <hip/hip_runtime.h>

#define B_ 32
#define C_ 128
#define H_ 64
#define W_ 64
#define HW_ (H_*W_)
#define NT_ (B_*(H_/2))      // 1024 tiles; tile = 2 rows = 128 px
#define EPS_ 1e-5f

typedef __attribute__((ext_vector_type(8))) short s8v;   // 8 bf16
typedef __attribute__((ext_vector_type(4))) float f4v;   // MFMA accumulator
typedef unsigned short u16;

__device__ __forceinline__ short f2bf(float f) {
    union { float f; unsigned u; } v; v.f = f;
    unsigned r = v.u + 0x7fffu + ((v.u >> 16) & 1u);     // RNE
    return (short)(r >> 16);
}
__device__ __forceinline__ float bf2f(u16 u) {
    union { unsigned u; float f; } v; v.u = ((unsigned)u) << 16; return v.f;
}

// dwx layout (u16 units), tile-local fragment-linear so GEMM B-reads are
// lane-linear 16B chunks:
//   off = tile*16384 + nt*2048 + kk*512 + kr*128 + q*8 + cj
// holds dw-output channel c = kk*32+kr*8+cj at pixel px = nt*16+q.
__device__ __forceinline__ size_t dwx_off(int tile, int nt, int kk, int kr, int q) {
    return (size_t)tile * 16384 + nt * 2048 + kk * 512 + kr * 128 + q * 8;
}

// Streaming depthwise (+BN1-on-read for block 2) + fragment-layout pack.
// 512 WGs x 256 thr: wave = one image row, lane = one pixel column.
// WGs 0/1 additionally pack pw1/pw2 into A-fragment order (block 1 only).
template<int BF16IN>
__global__ __launch_bounds__(256, 4) void dw_pack(
    const void*  __restrict__ xin_,
    const float* __restrict__ scale_in,   // BN params (BF16IN=1 only)
    const float* __restrict__ shift_in,
    const float* __restrict__ dww,        // [C][9]
    const float* __restrict__ pw1,
    const float* __restrict__ pw2,
    short* __restrict__ wf1,
    short* __restrict__ wf2,
    u16*   __restrict__ dwx)
{
    const int s = blockIdx.x;             // 512 slabs of 4 rows
    const int t = threadIdx.x;

    if (BF16IN == 0 && s < 2) {           // fold prep_wfrag into dw1
        const float* pw = (s == 0) ? pw1 : pw2;
        short* wf = (s == 0) ? wf1 : wf2;
        for (int i = t; i < 16384; i += 256) {
            int j = i & 7, lane = (i >> 3) & 63, kk = (i >> 9) & 3, mt = i >> 11;
            int o = mt * 16 + (lane & 15);
            int c = kk * 32 + (lane >> 4) * 8 + j;
            wf[i] = f2bf(pw[o * C_ + c]);
        }
    }

    const int n    = s >> 4;
    const int h    = (s & 15) * 4 + (t >> 6);   // wave -> row
    const int w    = t & 63;                     // lane -> column
    const int tile = n * 32 + (h >> 1);
    const int px   = (h & 1) * 64 + w;
    const int nt   = px >> 4, q = px & 15;

    for (int g = 0; g < 16; ++g) {
        const int c0 = g * 8;
        // batch-issue all 24 loads for this 8-channel group
        float v[8][3];
        #pragma unroll
        for (int cj = 0; cj < 8; ++cj) {
            const int c = c0 + cj;
            #pragma unroll
            for (int k = 0; k < 3; ++k) {
                const int hin = h - 1 + k;
                const int hc  = hin < 0 ? 0 : (hin >= H_ ? H_ - 1 : hin);
                if (BF16IN)
                    v[cj][k] = bf2f(((const u16*)xin_)[((size_t)(n * C_ + c)) * HW_ + hc * W_ + w]);
                else
                    v[cj][k] = ((const float*)xin_)[((size_t)(n * C_ + c)) * HW_ + hc * W_ + w];
            }
        }
        s8v out8;
        #pragma unroll
        for (int cj = 0; cj < 8; ++cj) {
            const int c = c0 + cj;
            float sc = 1.f, sh = 0.f;
            if (BF16IN) { sc = scale_in[c]; sh = shift_in[c]; }
            float m[3];
            #pragma unroll
            for (int k = 0; k < 3; ++k) {
                const int hin = h - 1 + k;
                float val = fmaxf(fmaf(v[cj][k], sc, sh), 0.f);
                if (hin < 0 || hin >= H_) val = 0.f;
                m[k] = val;
            }
            float l0 = __shfl_up(m[0], 1), l1 = __shfl_up(m[1], 1), l2 = __shfl_up(m[2], 1);
            float r0 = __shfl_down(m[0], 1), r1 = __shfl_down(m[1], 1), r2 = __shfl_down(m[2], 1);
            if (w == 0)  { l0 = 0.f; l1 = 0.f; l2 = 0.f; }
            if (w == 63) { r0 = 0.f; r1 = 0.f; r2 = 0.f; }
            const float* wc = dww + c * 9;
            float a;
            a = wc[0] * l0;
            a = fmaf(wc[1], m[0], a); a = fmaf(wc[2], r0, a);
            a = fmaf(wc[3], l1, a);  a = fmaf(wc[4], m[1], a); a = fmaf(wc[5], r1, a);
            a = fmaf(wc[6], l2, a);  a = fmaf(wc[7], m[2], a); a = fmaf(wc[8], r2, a);
            out8[cj] = f2bf(a);
        }
        *(s8v*)&dwx[dwx_off(tile, nt, c0 >> 5, (c0 >> 3) & 3, q)] = out8;
    }
}

// Pointwise GEMM straight from the fragment-linear dwx (L2/L3-resident, no
// LDS staging, no barriers) + fused partial stats + LDS-staged NCHW store.
// 1024 WGs x 256 thr (4 waves). Wave owns 32 o-rows x 128 px.
__global__ __launch_bounds__(256, 4) void gemm_stats(
    const u16*  __restrict__ dwx,
    const short* __restrict__ wfrag,
    u16*   __restrict__ yout,             // pre-BN y, bf16 NCHW
    float* __restrict__ psum,             // [NT_][C_]
    float* __restrict__ psq)              // [NT_][C_]
{
    __shared__ __align__(16) u16 stage[4 * 4096];   // 32 KiB, per-wave regions

    const int tile = blockIdx.x;
    const int t = threadIdx.x, lane = t & 63, wv = t >> 6;
    const int kr = lane >> 4, q = lane & 15;

    f4v acc[2][8];
    #pragma unroll
    for (int m = 0; m < 2; ++m)
        #pragma unroll
        for (int nt = 0; nt < 8; ++nt) acc[m][nt] = (f4v)(0.f);

    const u16* db = dwx + (size_t)tile * 16384;
    #pragma unroll
    for (int kk = 0; kk < 4; ++kk) {
        s8v a0 = *(const s8v*)&wfrag[(((wv * 2    ) * 4 + kk) * 64 + lane) * 8];
        s8v a1 = *(const s8v*)&wfrag[(((wv * 2 + 1) * 4 + kk) * 64 + lane) * 8];
        #pragma unroll
        for (int nt = 0; nt < 8; ++nt) {
            s8v b = *(const s8v*)&db[nt * 2048 + kk * 512 + kr * 128 + q * 8];
            acc[0][nt] = __builtin_amdgcn_mfma_f32_16x16x32_bf16(a0, b, acc[0][nt], 0, 0, 0);
            acc[1][nt] = __builtin_amdgcn_mfma_f32_16x16x32_bf16(a1, b, acc[1][nt], 0, 0, 0);
        }
    }

    // fused partial stats + stage write (per-wave region, no barrier needed)
    #pragma unroll
    for (int m = 0; m < 2; ++m) {
        #pragma unroll
        for (int ri = 0; ri < 4; ++ri) {
            const int ol = m * 16 + kr * 4 + ri;   // o within wave's 32
            float s = 0.f, qq = 0.f;
            #pragma unroll
            for (int nt = 0; nt < 8; ++nt) {
                const float val = acc[m][nt][ri];
                s += val; qq = fmaf(val, val, qq);
            }
            s += __shfl_xor(s, 1); qq += __shfl_xor(qq, 1);
            s += __shfl_xor(s, 2); qq += __shfl_xor(qq, 2);
            s += __shfl_xor(s, 4); qq += __shfl_xor(qq, 4);
            s += __shfl_xor(s, 8); qq += __shfl_xor(qq, 8);
            if (q == 0) {
                const int o = wv * 32 + ol;
                psum[(size_t)tile * C_ + o] = s;
                psq [(size_t)tile * C_ + o] = qq;
            }
            #pragma unroll
            for (int nt = 0; nt < 8; ++nt)
                stage[(wv * 4096 + ol * 128 + nt * 16 + q) ^ ((ol & 7) << 3)] =
                    (u16)f2bf(acc[m][nt][ri]);
        }
    }

    const int n = tile >> 5, h0 = (tile & 31) * 2;
    #pragma unroll
    for (int oi = 0; oi < 8; ++oi) {
        const int ol = oi * 4 + kr;
        const uint4 v = *(const uint4*)((const char*)stage +
            (((wv * 4096 + ol * 128 + q * 8) * 2) ^ ((ol & 7) << 4)));
        const int o = wv * 32 + ol;
        *(uint4*)((char*)(yout + ((size_t)(n * C_ + o)) * HW_ + h0 * W_) + q * 16) = v;
    }
}

// One WG per channel: reduce NT_ partials -> scale/shift.
__global__ __launch_bounds__(256) void stats_reduce(const float* __restrict__ psum,
                                                    const float* __restrict__ psq,
                                                    const float* __restrict__ gamma,
                                                    const float* __restrict__ beta,
                                                    float* __restrict__ scale,
                                                    float* __restrict__ shift) {
    const int o = blockIdx.x;
    const int t = threadIdx.x;
    float s = 0.f, q = 0.f;
    for (int i = t; i < NT_; i += 256) {
        s += psum[(size_t)i * C_ + o];
        q += psq [(size_t)i * C_ + o];
    }
    #pragma unroll
    for (int off = 32; off > 0; off >>= 1) {
        s += __shfl_down(s, off);
        q += __shfl_down(q, off);
    }
    __shared__ float rs[4], rq[4];
    const int wid = t >> 6;
    if ((t & 63) == 0) { rs[wid] = s; rq[wid] = q; }
    __syncthreads();
    if (t == 0) {
        float S = rs[0] + rs[1] + rs[2] + rs[3];
        float Q = rq[0] + rq[1] + rq[2] + rq[3];
        const float inv = 1.f / (float)(B_ * HW_);
        float mean = S * inv;
        float var  = Q * inv - mean * mean;
        float sc   = gamma[o] * rsqrtf(var + EPS_);
        scale[o] = sc;
        shift[o] = fmaf(-mean, sc, beta[o]);
    }
}

// BN apply: read bf16 y2, write fp32 out.
__global__ __launch_bounds__(256) void apply_bn(const u16* __restrict__ y,
                                                float* __restrict__ out,
                                                const float* __restrict__ scale,
                                                const float* __restrict__ shift) {
    const size_t total8 = (size_t)B_ * C_ * HW_ / 8;
    const size_t stride = (size_t)gridDim.x * 256;
    for (size_t i = (size_t)blockIdx.x * 256 + threadIdx.x; i < total8; i += stride) {
        const size_t e = i * 8;
        const int c = (int)((e >> 12) & (C_ - 1));
        const float sc = scale[c], sh = shift[c];
        s8v v = *(const s8v*)(y + e);
        float4 o1, o2;
        o1.x = fmaf(bf2f((u16)v[0]), sc, sh);
        o1.y = fmaf(bf2f((u16)v[1]), sc, sh);
        o1.z = fmaf(bf2f((u16)v[2]), sc, sh);
        o1.w = fmaf(bf2f((u16)v[3]), sc, sh);
        o2.x = fmaf(bf2f((u16)v[4]), sc, sh);
        o2.y = fmaf(bf2f((u16)v[5]), sc, sh);
        o2.z = fmaf(bf2f((u16)v[6]), sc, sh);
        o2.w = fmaf(bf2f((u16)v[7]), sc, sh);
        *(float4*)(out + e)     = o1;
        *(float4*)(out + e + 4) = o2;
    }
}

extern "C" void kernel_launch(void* const* d_in, const int* in_sizes, int n_in,
                              void* d_out, int out_size, void* d_ws, size_t ws_size,
                              hipStream_t stream) {
    const float* x      = (const float*)d_in[0];
    const float* dw1    = (const float*)d_in[1];
    const float* pw1    = (const float*)d_in[2];
    const float* gamma1 = (const float*)d_in[3];
    const float* beta1  = (const float*)d_in[4];
    const float* dw2    = (const float*)d_in[5];
    const float* pw2    = (const float*)d_in[6];
    const float* gamma2 = (const float*)d_in[7];
    const float* beta2  = (const float*)d_in[8];
    float* out = (float*)d_out;
    char*  ws  = (char*)d_ws;

    short* wf1    = (short*)(ws);                          // 32 KiB
    short* wf2    = (short*)(ws + 32768);                  // 32 KiB
    float* scale1 = (float*)(ws + 65536);
    float* shift1 = (float*)(ws + 66048);
    float* scale2 = (float*)(ws + 66560);
    float* shift2 = (float*)(ws + 67072);
    float* psum   = (float*)(ws + 67584);                  // 512 KiB
    float* psq    = (float*)(ws + 67584 + 524288);         // 512 KiB
    u16*   dwx    = (u16*)(ws + 67584 + 1048576);          // 32 MiB
    u16*   y12    = (u16*)(ws + 67584 + 1048576 + 33554432); // 32 MiB (y1, then y2)

    dw_pack<0><<<512, 256, 0, stream>>>(x, nullptr, nullptr, dw1, pw1, pw2, wf1, wf2, dwx);
    gemm_stats<<<NT_, 256, 0, stream>>>(dwx, wf1, y12, psum, psq);
    stats_reduce<<<C_, 256, 0, stream>>>(psum, psq, gamma1, beta1, scale1, shift1);
    dw_pack<1><<<512, 256, 0, stream>>>(y12, scale1, shift1, dw2, pw1, pw2, wf1, wf2, dwx);
    gemm_stats<<<NT_, 256, 0, stream>>>(dwx, wf2, y12, psum, psq);
    stats_reduce<<<C_, 256, 0, stream>>>(psum, psq, gamma2, beta2, scale2, shift2);
    apply_bn<<<2048, 256, 0, stream>>>(y12, out, scale2, shift2);
}